// Round 1
// baseline (986.467 us; speedup 1.0000x reference)
//
#include <hip/hip_runtime.h>

namespace {
constexpr int CCH = 256;   // channels
constexpr int OUT = 7;     // output size
constexpr int S   = 14;    // OUT * SAMPLE_NUM
constexpr int NUM_ROIS = 1024;
}

__global__ __launch_bounds__(256) void roi_extract(
    const float* __restrict__ f0, const float* __restrict__ f1,
    const float* __restrict__ f2, const float* __restrict__ f3,
    const float* __restrict__ rois, float* __restrict__ out)
{
    const int k = blockIdx.x;
    const int t = threadIdx.x;

    // Separable bilinear sample metadata: axis 0 = y (row offsets), axis 1 = x
    __shared__ float s_wlo[2][S];
    __shared__ float s_whi[2][S];
    __shared__ int   s_olo[2][S];
    __shared__ int   s_ohi[2][S];

    const float rb  = rois[k*5+0];
    const float rx1 = rois[k*5+1];
    const float ry1 = rois[k*5+2];
    const float rx2 = rois[k*5+3];
    const float ry2 = rois[k*5+4];

    // level selection (uniform per block)
    const float sc = sqrtf((rx2 - rx1 + 1.0f) * (ry2 - ry1 + 1.0f));
    int lvl = (int)floorf(log2f(sc * (1.0f/56.0f) + 1e-6f));
    lvl = lvl < 0 ? 0 : (lvl > 3 ? 3 : lvl);

    const float* fp; int H, W; float sp;
    if (lvl == 0)      { fp = f0; H = 200; W = 304; sp = 0.25f;    }
    else if (lvl == 1) { fp = f1; H = 100; W = 152; sp = 0.125f;   }
    else if (lvl == 2) { fp = f2; H = 50;  W = 76;  sp = 0.0625f;  }
    else               { fp = f3; H = 25;  W = 38;  sp = 0.03125f; }

    if (t < 2*S) {
        const int axis = (t >= S) ? 1 : 0;     // 0=y, 1=x
        const int i = axis ? (t - S) : t;
        const float lo = (axis ? rx1 : ry1) * sp;
        const float hi = (axis ? rx2 : ry2) * sp;
        const int dim  = axis ? W : H;
        const float len = fmaxf(hi - lo, 1.0f);
        const float bin = len * (1.0f / (float)S);   // roi_len / S first, like ref
        const float v = lo + ((float)i + 0.5f) * bin;
        const bool valid = (v >= -1.0f) && (v <= (float)dim);
        float vc = fmaxf(v, 0.0f);
        int l = (int)floorf(vc);
        if (l >= dim - 1) { vc = (float)(dim - 1); l = dim - 1; }
        const int h = min(l + 1, dim - 1);
        const float frac = vc - (float)l;
        float wlo = 1.0f - frac;   // hy / hx
        float whi = frac;          // ly / lx
        if (!valid) { wlo = 0.0f; whi = 0.0f; }
        const int mul = axis ? 1 : W;
        s_wlo[axis][i] = wlo;
        s_whi[axis][i] = whi;
        s_olo[axis][i] = l * mul;
        s_ohi[axis][i] = h * mul;
    }
    __syncthreads();

    const int b = (int)rb;
    const float* __restrict__ base =
        fp + (size_t)(b * CCH + t) * (size_t)(H * W);
    float* __restrict__ obase = out + ((size_t)k * CCH + t) * (OUT * OUT);

    for (int oh = 0; oh < OUT; ++oh) {
        const int sy0 = oh * 2;
        const float hy0 = s_wlo[0][sy0],   ly0 = s_whi[0][sy0];
        const float hy1 = s_wlo[0][sy0+1], ly1 = s_whi[0][sy0+1];
        const int oyl0 = s_olo[0][sy0],   oyh0 = s_ohi[0][sy0];
        const int oyl1 = s_olo[0][sy0+1], oyh1 = s_ohi[0][sy0+1];
        #pragma unroll
        for (int ow = 0; ow < OUT; ++ow) {
            float acc = 0.0f;
            #pragma unroll
            for (int dx = 0; dx < 2; ++dx) {
                const int sx = ow * 2 + dx;
                const float hx = s_wlo[1][sx];
                const float lx = s_whi[1][sx];
                const int oxl = s_olo[1][sx];
                const int oxh = s_ohi[1][sx];
                acc += hy0 * (hx * base[oyl0 + oxl] + lx * base[oyl0 + oxh])
                     + ly0 * (hx * base[oyh0 + oxl] + lx * base[oyh0 + oxh])
                     + hy1 * (hx * base[oyl1 + oxl] + lx * base[oyl1 + oxh])
                     + ly1 * (hx * base[oyh1 + oxl] + lx * base[oyh1 + oxh]);
            }
            obase[oh * OUT + ow] = acc * 0.25f;
        }
    }
}

extern "C" void kernel_launch(void* const* d_in, const int* in_sizes, int n_in,
                              void* d_out, int out_size, void* d_ws, size_t ws_size,
                              hipStream_t stream) {
    const float* f0   = (const float*)d_in[0];
    const float* f1   = (const float*)d_in[1];
    const float* f2   = (const float*)d_in[2];
    const float* f3   = (const float*)d_in[3];
    const float* rois = (const float*)d_in[4];
    float* out = (float*)d_out;
    roi_extract<<<NUM_ROIS, 256, 0, stream>>>(f0, f1, f2, f3, rois, out);
}

// Round 2
// 292.534 us; speedup vs baseline: 3.3721x; 3.3721x over previous
//
#include <hip/hip_runtime.h>

namespace {
constexpr int CCH = 256;   // channels
constexpr int OUT = 7;     // output size
constexpr int S   = 14;    // OUT * SAMPLE_NUM
constexpr int NUM_ROIS = 1024;

constexpr int H0 = 200, W0 = 304;
constexpr int H1 = 100, W1 = 152;
constexpr int H2 = 50,  W2 = 76;
constexpr int H3 = 25,  W3 = 38;

constexpr size_t NW0 = (size_t)2 * H0 * W0 * CCH;  // floats per transposed level
constexpr size_t NW1 = (size_t)2 * H1 * W1 * CCH;
constexpr size_t NW2 = (size_t)2 * H2 * W2 * CCH;
constexpr size_t NW3 = (size_t)2 * H3 * W3 * CCH;
}

// ---------------- NCHW -> NHWC transpose (per level) ----------------
// Tile: 32 x-positions x 256 channels, staged through LDS (pad 257 -> conflict-free).
__global__ __launch_bounds__(256) void transpose_nchw_nhwc(
    const float* __restrict__ in, float* __restrict__ outp, int H, int W)
{
    __shared__ float lds[32][257];
    const int x0 = blockIdx.x * 32;
    const int y  = blockIdx.y;
    const int b  = blockIdx.z;
    const int t  = threadIdx.x;
    const int xr = t & 31;
    const int cb = t >> 5;   // 0..7

    const int x = x0 + xr;
    #pragma unroll 4
    for (int i = 0; i < 32; ++i) {
        const int c = cb + (i << 3);
        float v = 0.0f;
        if (x < W) v = in[((size_t)(b * CCH + c) * H + y) * W + x];
        lds[xr][c] = v;
    }
    __syncthreads();
    #pragma unroll 4
    for (int i = 0; i < 32; ++i) {
        const int xo = x0 + i;
        if (xo < W) outp[(((size_t)b * H + y) * W + xo) * CCH + t] = lds[i][t];
    }
}

// ---------------- gather from NHWC ----------------
__global__ __launch_bounds__(256) void roi_gather(
    const float* __restrict__ w0, const float* __restrict__ w1,
    const float* __restrict__ w2, const float* __restrict__ w3,
    const float* __restrict__ rois, float* __restrict__ out)
{
    const int k = blockIdx.x;
    const int t = threadIdx.x;

    __shared__ float s_wlo[2][S];
    __shared__ float s_whi[2][S];
    __shared__ int   s_olo[2][S];   // element offsets in NHWC (y: *W*C, x: *C)
    __shared__ int   s_ohi[2][S];

    const float rb  = rois[k*5+0];
    const float rx1 = rois[k*5+1];
    const float ry1 = rois[k*5+2];
    const float rx2 = rois[k*5+3];
    const float ry2 = rois[k*5+4];

    const float sc = sqrtf((rx2 - rx1 + 1.0f) * (ry2 - ry1 + 1.0f));
    int lvl = (int)floorf(log2f(sc * (1.0f/56.0f) + 1e-6f));
    lvl = lvl < 0 ? 0 : (lvl > 3 ? 3 : lvl);

    const float* fp; int H, W; float sp;
    if (lvl == 0)      { fp = w0; H = H0; W = W0; sp = 0.25f;    }
    else if (lvl == 1) { fp = w1; H = H1; W = W1; sp = 0.125f;   }
    else if (lvl == 2) { fp = w2; H = H2; W = W2; sp = 0.0625f;  }
    else               { fp = w3; H = H3; W = W3; sp = 0.03125f; }

    if (t < 2*S) {
        const int axis = (t >= S) ? 1 : 0;     // 0=y, 1=x
        const int i = axis ? (t - S) : t;
        const float lo = (axis ? rx1 : ry1) * sp;
        const float hi = (axis ? rx2 : ry2) * sp;
        const int dim  = axis ? W : H;
        const float len = fmaxf(hi - lo, 1.0f);
        const float bin = len * (1.0f / (float)S);
        const float v = lo + ((float)i + 0.5f) * bin;
        const bool valid = (v >= -1.0f) && (v <= (float)dim);
        float vc = fmaxf(v, 0.0f);
        int l = (int)floorf(vc);
        if (l >= dim - 1) { vc = (float)(dim - 1); l = dim - 1; }
        const int h = min(l + 1, dim - 1);
        const float frac = vc - (float)l;
        float wlo = 1.0f - frac;
        float whi = frac;
        if (!valid) { wlo = 0.0f; whi = 0.0f; }
        const int mul = axis ? CCH : W * CCH;
        s_wlo[axis][i] = wlo;
        s_whi[axis][i] = whi;
        s_olo[axis][i] = l * mul;
        s_ohi[axis][i] = h * mul;
    }
    __syncthreads();

    const int b = (int)rb;
    const float* __restrict__ base = fp + (size_t)b * H * W * CCH + t;
    float* __restrict__ obase = out + ((size_t)k * CCH + t) * (OUT * OUT);

    for (int oh = 0; oh < OUT; ++oh) {
        const int sy0 = oh * 2;
        const float hy0 = s_wlo[0][sy0],   ly0 = s_whi[0][sy0];
        const float hy1 = s_wlo[0][sy0+1], ly1 = s_whi[0][sy0+1];
        const int oyl0 = s_olo[0][sy0],   oyh0 = s_ohi[0][sy0];
        const int oyl1 = s_olo[0][sy0+1], oyh1 = s_ohi[0][sy0+1];
        #pragma unroll
        for (int ow = 0; ow < OUT; ++ow) {
            float acc = 0.0f;
            #pragma unroll
            for (int dx = 0; dx < 2; ++dx) {
                const int sx = ow * 2 + dx;
                const float hx = s_wlo[1][sx];
                const float lx = s_whi[1][sx];
                const int oxl = s_olo[1][sx];
                const int oxh = s_ohi[1][sx];
                acc += hy0 * (hx * base[oyl0 + oxl] + lx * base[oyl0 + oxh])
                     + ly0 * (hx * base[oyh0 + oxl] + lx * base[oyh0 + oxh])
                     + hy1 * (hx * base[oyl1 + oxl] + lx * base[oyl1 + oxh])
                     + ly1 * (hx * base[oyh1 + oxl] + lx * base[oyh1 + oxh]);
            }
            obase[oh * OUT + ow] = acc * 0.25f;
        }
    }
}

// ---------------- fallback (round-0 kernel) if ws too small ----------------
__global__ __launch_bounds__(256) void roi_extract_direct(
    const float* __restrict__ f0, const float* __restrict__ f1,
    const float* __restrict__ f2, const float* __restrict__ f3,
    const float* __restrict__ rois, float* __restrict__ out)
{
    const int k = blockIdx.x;
    const int t = threadIdx.x;

    __shared__ float s_wlo[2][S];
    __shared__ float s_whi[2][S];
    __shared__ int   s_olo[2][S];
    __shared__ int   s_ohi[2][S];

    const float rb  = rois[k*5+0];
    const float rx1 = rois[k*5+1];
    const float ry1 = rois[k*5+2];
    const float rx2 = rois[k*5+3];
    const float ry2 = rois[k*5+4];

    const float sc = sqrtf((rx2 - rx1 + 1.0f) * (ry2 - ry1 + 1.0f));
    int lvl = (int)floorf(log2f(sc * (1.0f/56.0f) + 1e-6f));
    lvl = lvl < 0 ? 0 : (lvl > 3 ? 3 : lvl);

    const float* fp; int H, W; float sp;
    if (lvl == 0)      { fp = f0; H = H0; W = W0; sp = 0.25f;    }
    else if (lvl == 1) { fp = f1; H = H1; W = W1; sp = 0.125f;   }
    else if (lvl == 2) { fp = f2; H = H2; W = W2; sp = 0.0625f;  }
    else               { fp = f3; H = H3; W = W3; sp = 0.03125f; }

    if (t < 2*S) {
        const int axis = (t >= S) ? 1 : 0;
        const int i = axis ? (t - S) : t;
        const float lo = (axis ? rx1 : ry1) * sp;
        const float hi = (axis ? rx2 : ry2) * sp;
        const int dim  = axis ? W : H;
        const float len = fmaxf(hi - lo, 1.0f);
        const float bin = len * (1.0f / (float)S);
        const float v = lo + ((float)i + 0.5f) * bin;
        const bool valid = (v >= -1.0f) && (v <= (float)dim);
        float vc = fmaxf(v, 0.0f);
        int l = (int)floorf(vc);
        if (l >= dim - 1) { vc = (float)(dim - 1); l = dim - 1; }
        const int h = min(l + 1, dim - 1);
        const float frac = vc - (float)l;
        float wlo = 1.0f - frac;
        float whi = frac;
        if (!valid) { wlo = 0.0f; whi = 0.0f; }
        const int mul = axis ? 1 : W;
        s_wlo[axis][i] = wlo;
        s_whi[axis][i] = whi;
        s_olo[axis][i] = l * mul;
        s_ohi[axis][i] = h * mul;
    }
    __syncthreads();

    const int b = (int)rb;
    const float* __restrict__ base = fp + (size_t)(b * CCH + t) * (size_t)(H * W);
    float* __restrict__ obase = out + ((size_t)k * CCH + t) * (OUT * OUT);

    for (int oh = 0; oh < OUT; ++oh) {
        const int sy0 = oh * 2;
        const float hy0 = s_wlo[0][sy0],   ly0 = s_whi[0][sy0];
        const float hy1 = s_wlo[0][sy0+1], ly1 = s_whi[0][sy0+1];
        const int oyl0 = s_olo[0][sy0],   oyh0 = s_ohi[0][sy0];
        const int oyl1 = s_olo[0][sy0+1], oyh1 = s_ohi[0][sy0+1];
        #pragma unroll
        for (int ow = 0; ow < OUT; ++ow) {
            float acc = 0.0f;
            #pragma unroll
            for (int dx = 0; dx < 2; ++dx) {
                const int sx = ow * 2 + dx;
                const float hx = s_wlo[1][sx];
                const float lx = s_whi[1][sx];
                const int oxl = s_olo[1][sx];
                const int oxh = s_ohi[1][sx];
                acc += hy0 * (hx * base[oyl0 + oxl] + lx * base[oyl0 + oxh])
                     + ly0 * (hx * base[oyh0 + oxl] + lx * base[oyh0 + oxh])
                     + hy1 * (hx * base[oyl1 + oxl] + lx * base[oyl1 + oxh])
                     + ly1 * (hx * base[oyh1 + oxl] + lx * base[oyh1 + oxh]);
            }
            obase[oh * OUT + ow] = acc * 0.25f;
        }
    }
}

extern "C" void kernel_launch(void* const* d_in, const int* in_sizes, int n_in,
                              void* d_out, int out_size, void* d_ws, size_t ws_size,
                              hipStream_t stream) {
    const float* f0   = (const float*)d_in[0];
    const float* f1   = (const float*)d_in[1];
    const float* f2   = (const float*)d_in[2];
    const float* f3   = (const float*)d_in[3];
    const float* rois = (const float*)d_in[4];
    float* out = (float*)d_out;

    const size_t need_bytes = (NW0 + NW1 + NW2 + NW3) * sizeof(float);
    if (ws_size >= need_bytes) {
        float* ws0 = (float*)d_ws;
        float* ws1 = ws0 + NW0;
        float* ws2 = ws1 + NW1;
        float* ws3 = ws2 + NW2;
        transpose_nchw_nhwc<<<dim3((W0+31)/32, H0, 2), 256, 0, stream>>>(f0, ws0, H0, W0);
        transpose_nchw_nhwc<<<dim3((W1+31)/32, H1, 2), 256, 0, stream>>>(f1, ws1, H1, W1);
        transpose_nchw_nhwc<<<dim3((W2+31)/32, H2, 2), 256, 0, stream>>>(f2, ws2, H2, W2);
        transpose_nchw_nhwc<<<dim3((W3+31)/32, H3, 2), 256, 0, stream>>>(f3, ws3, H3, W3);
        roi_gather<<<NUM_ROIS, 256, 0, stream>>>(ws0, ws1, ws2, ws3, rois, out);
    } else {
        roi_extract_direct<<<NUM_ROIS, 256, 0, stream>>>(f0, f1, f2, f3, rois, out);
    }
}

// Round 3
// 171.060 us; speedup vs baseline: 5.7668x; 1.7101x over previous
//
#include <hip/hip_runtime.h>

namespace {
constexpr int CCH = 256;   // channels
constexpr int OUT = 7;     // output size
constexpr int S   = 14;    // OUT * SAMPLE_NUM
constexpr int NUM_ROIS = 1024;

constexpr int H0 = 200, W0 = 304;
constexpr int H1 = 100, W1 = 152;
constexpr int H2 = 50,  W2 = 76;
constexpr int H3 = 25,  W3 = 38;

constexpr size_t NW0 = (size_t)2 * H0 * W0 * CCH;  // floats per transposed level
constexpr size_t NW1 = (size_t)2 * H1 * W1 * CCH;
constexpr size_t NW2 = (size_t)2 * H2 * W2 * CCH;
constexpr size_t NW3 = (size_t)2 * H3 * W3 * CCH;
}

// ---------------- NCHW -> NHWC transpose, float4 fast path (W % 4 == 0) ----
// Tile: 32 x-positions x 256 channels. LDS row stride 260 (16B-aligned, breaks
// power-of-2 strides).
__global__ __launch_bounds__(256) void transpose_f4(
    const float* __restrict__ in, float* __restrict__ outp, int H, int W)
{
    __shared__ float lds[32 * 260];
    const int x0 = blockIdx.x * 32;
    const int y  = blockIdx.y;
    const int b  = blockIdx.z;
    const int t  = threadIdx.x;

    // Phase A: float4 loads along x. thread: xq = t&7 (8 quads = 32 x), c-group = t>>3
    {
        const int xq = t & 7;
        const int c0 = t >> 3;           // 0..31
        const int x  = x0 + 4 * xq;
        #pragma unroll
        for (int i = 0; i < 8; ++i) {
            const int c = c0 + (i << 5);
            float4 v = make_float4(0.f, 0.f, 0.f, 0.f);
            if (x + 3 < W)   // W%4==0 and x%4==0 -> quad fully valid or fully not
                v = *reinterpret_cast<const float4*>(
                        in + (((size_t)(b * CCH + c) * H + y) * W + x));
            float* row = &lds[(4 * xq) * 260 + c];
            row[0 * 260] = v.x;
            row[1 * 260] = v.y;
            row[2 * 260] = v.z;
            row[3 * 260] = v.w;
        }
    }
    __syncthreads();
    // Phase B: float4 coalesced stores along c. wave handles 8 consecutive x.
    {
        const int co = t & 63;           // float4 group: channels 4co..4co+3
        const int wv = t >> 6;           // 0..3
        #pragma unroll
        for (int i = 0; i < 8; ++i) {
            const int xr = (wv << 3) + i;
            const int x  = x0 + xr;
            if (x < W) {
                float4 v = *reinterpret_cast<const float4*>(&lds[xr * 260 + 4 * co]);
                *reinterpret_cast<float4*>(
                    outp + ((((size_t)b * H + y) * W + x) * CCH + 4 * co)) = v;
            }
        }
    }
}

// ---------------- scalar transpose (any W) — used for level 3 ----------------
__global__ __launch_bounds__(256) void transpose_scalar(
    const float* __restrict__ in, float* __restrict__ outp, int H, int W)
{
    __shared__ float lds[32][257];
    const int x0 = blockIdx.x * 32;
    const int y  = blockIdx.y;
    const int b  = blockIdx.z;
    const int t  = threadIdx.x;
    const int xr = t & 31;
    const int cb = t >> 5;

    const int x = x0 + xr;
    #pragma unroll 4
    for (int i = 0; i < 32; ++i) {
        const int c = cb + (i << 3);
        float v = 0.0f;
        if (x < W) v = in[((size_t)(b * CCH + c) * H + y) * W + x];
        lds[xr][c] = v;
    }
    __syncthreads();
    #pragma unroll 4
    for (int i = 0; i < 32; ++i) {
        const int xo = x0 + i;
        if (xo < W) outp[(((size_t)b * H + y) * W + xo) * CCH + t] = lds[i][t];
    }
}

// ---------------- gather from NHWC (float2 lanes, LDS-staged output) --------
// grid: (NUM_ROIS, 2) — gy = channel half. block: 256 = 4 waves; wave w takes
// bins w, w+4, ... of the 49 output bins. lane l -> channels c_base+2l, +1.
__global__ __launch_bounds__(256) void roi_gather(
    const float* __restrict__ w0, const float* __restrict__ w1,
    const float* __restrict__ w2, const float* __restrict__ w3,
    const float* __restrict__ rois, float* __restrict__ out)
{
    const int k  = blockIdx.x;
    const int gy = blockIdx.y;          // channel half: 0 or 1
    const int t  = threadIdx.x;

    __shared__ float s_wlo[2][S];
    __shared__ float s_whi[2][S];
    __shared__ int   s_olo[2][S];   // offsets in float2 units (y: W*128, x: 128)
    __shared__ int   s_ohi[2][S];
    __shared__ float s_out[128 * 49];

    const float rb  = rois[k*5+0];
    const float rx1 = rois[k*5+1];
    const float ry1 = rois[k*5+2];
    const float rx2 = rois[k*5+3];
    const float ry2 = rois[k*5+4];

    const float sc = sqrtf((rx2 - rx1 + 1.0f) * (ry2 - ry1 + 1.0f));
    int lvl = (int)floorf(log2f(sc * (1.0f/56.0f) + 1e-6f));
    lvl = lvl < 0 ? 0 : (lvl > 3 ? 3 : lvl);

    const float* fp; int H, W; float sp;
    if (lvl == 0)      { fp = w0; H = H0; W = W0; sp = 0.25f;    }
    else if (lvl == 1) { fp = w1; H = H1; W = W1; sp = 0.125f;   }
    else if (lvl == 2) { fp = w2; H = H2; W = W2; sp = 0.0625f;  }
    else               { fp = w3; H = H3; W = W3; sp = 0.03125f; }

    if (t < 2*S) {
        const int axis = (t >= S) ? 1 : 0;     // 0=y, 1=x
        const int i = axis ? (t - S) : t;
        const float lo = (axis ? rx1 : ry1) * sp;
        const float hi = (axis ? rx2 : ry2) * sp;
        const int dim  = axis ? W : H;
        const float len = fmaxf(hi - lo, 1.0f);
        const float bin = len * (1.0f / (float)S);
        const float v = lo + ((float)i + 0.5f) * bin;
        const bool valid = (v >= -1.0f) && (v <= (float)dim);
        float vc = fmaxf(v, 0.0f);
        int l = (int)floorf(vc);
        if (l >= dim - 1) { vc = (float)(dim - 1); l = dim - 1; }
        const int h = min(l + 1, dim - 1);
        const float frac = vc - (float)l;
        float wlo = 1.0f - frac;
        float whi = frac;
        if (!valid) { wlo = 0.0f; whi = 0.0f; }
        const int mul = axis ? 128 : W * 128;   // float2 units
        s_wlo[axis][i] = wlo;
        s_whi[axis][i] = whi;
        s_olo[axis][i] = l * mul;
        s_ohi[axis][i] = h * mul;
    }
    __syncthreads();

    const int b = (int)rb;
    const int lane = t & 63;
    const int wv   = t >> 6;
    const float2* __restrict__ base =
        reinterpret_cast<const float2*>(fp + (size_t)b * H * W * CCH + gy * 128) + lane;

    for (int bin = wv; bin < OUT * OUT; bin += 4) {
        const int oh = bin / 7;
        const int ow = bin - oh * 7;
        const int sy0 = oh * 2;
        const int sx0 = ow * 2;
        float accx = 0.0f, accy = 0.0f;
        #pragma unroll
        for (int dy = 0; dy < 2; ++dy) {
            const float hy = s_wlo[0][sy0 + dy];
            const float ly = s_whi[0][sy0 + dy];
            const int oyl = s_olo[0][sy0 + dy];
            const int oyh = s_ohi[0][sy0 + dy];
            #pragma unroll
            for (int dx = 0; dx < 2; ++dx) {
                const float hx = s_wlo[1][sx0 + dx];
                const float lx = s_whi[1][sx0 + dx];
                const int oxl = s_olo[1][sx0 + dx];
                const int oxh = s_ohi[1][sx0 + dx];
                const float2 vll = base[oyl + oxl];
                const float2 vlh = base[oyl + oxh];
                const float2 vhl = base[oyh + oxl];
                const float2 vhh = base[oyh + oxh];
                const float wll = hy * hx, wlh = hy * lx;
                const float whl = ly * hx, whh = ly * lx;
                accx += wll * vll.x + wlh * vlh.x + whl * vhl.x + whh * vhh.x;
                accy += wll * vll.y + wlh * vlh.y + whl * vhl.y + whh * vhh.y;
            }
        }
        s_out[(2 * lane)     * 49 + bin] = accx * 0.25f;
        s_out[(2 * lane + 1) * 49 + bin] = accy * 0.25f;
    }
    __syncthreads();

    float* __restrict__ ob = out + ((size_t)k * CCH + gy * 128) * (OUT * OUT);
    #pragma unroll
    for (int i = t; i < 128 * 49; i += 256) ob[i] = s_out[i];
}

// ---------------- fallback (direct NCHW) if ws too small ----------------
__global__ __launch_bounds__(256) void roi_extract_direct(
    const float* __restrict__ f0, const float* __restrict__ f1,
    const float* __restrict__ f2, const float* __restrict__ f3,
    const float* __restrict__ rois, float* __restrict__ out)
{
    const int k = blockIdx.x;
    const int t = threadIdx.x;

    __shared__ float s_wlo[2][S];
    __shared__ float s_whi[2][S];
    __shared__ int   s_olo[2][S];
    __shared__ int   s_ohi[2][S];

    const float rb  = rois[k*5+0];
    const float rx1 = rois[k*5+1];
    const float ry1 = rois[k*5+2];
    const float rx2 = rois[k*5+3];
    const float ry2 = rois[k*5+4];

    const float sc = sqrtf((rx2 - rx1 + 1.0f) * (ry2 - ry1 + 1.0f));
    int lvl = (int)floorf(log2f(sc * (1.0f/56.0f) + 1e-6f));
    lvl = lvl < 0 ? 0 : (lvl > 3 ? 3 : lvl);

    const float* fp; int H, W; float sp;
    if (lvl == 0)      { fp = f0; H = H0; W = W0; sp = 0.25f;    }
    else if (lvl == 1) { fp = f1; H = H1; W = W1; sp = 0.125f;   }
    else if (lvl == 2) { fp = f2; H = H2; W = W2; sp = 0.0625f;  }
    else               { fp = f3; H = H3; W = W3; sp = 0.03125f; }

    if (t < 2*S) {
        const int axis = (t >= S) ? 1 : 0;
        const int i = axis ? (t - S) : t;
        const float lo = (axis ? rx1 : ry1) * sp;
        const float hi = (axis ? rx2 : ry2) * sp;
        const int dim  = axis ? W : H;
        const float len = fmaxf(hi - lo, 1.0f);
        const float bin = len * (1.0f / (float)S);
        const float v = lo + ((float)i + 0.5f) * bin;
        const bool valid = (v >= -1.0f) && (v <= (float)dim);
        float vc = fmaxf(v, 0.0f);
        int l = (int)floorf(vc);
        if (l >= dim - 1) { vc = (float)(dim - 1); l = dim - 1; }
        const int h = min(l + 1, dim - 1);
        const float frac = vc - (float)l;
        float wlo = 1.0f - frac;
        float whi = frac;
        if (!valid) { wlo = 0.0f; whi = 0.0f; }
        const int mul = axis ? 1 : W;
        s_wlo[axis][i] = wlo;
        s_whi[axis][i] = whi;
        s_olo[axis][i] = l * mul;
        s_ohi[axis][i] = h * mul;
    }
    __syncthreads();

    const int b = (int)rb;
    const float* __restrict__ base = fp + (size_t)(b * CCH + t) * (size_t)(H * W);
    float* __restrict__ obase = out + ((size_t)k * CCH + t) * (OUT * OUT);

    for (int oh = 0; oh < OUT; ++oh) {
        const int sy0 = oh * 2;
        const float hy0 = s_wlo[0][sy0],   ly0 = s_whi[0][sy0];
        const float hy1 = s_wlo[0][sy0+1], ly1 = s_whi[0][sy0+1];
        const int oyl0 = s_olo[0][sy0],   oyh0 = s_ohi[0][sy0];
        const int oyl1 = s_olo[0][sy0+1], oyh1 = s_ohi[0][sy0+1];
        #pragma unroll
        for (int ow = 0; ow < OUT; ++ow) {
            float acc = 0.0f;
            #pragma unroll
            for (int dx = 0; dx < 2; ++dx) {
                const int sx = ow * 2 + dx;
                const float hx = s_wlo[1][sx];
                const float lx = s_whi[1][sx];
                const int oxl = s_olo[1][sx];
                const int oxh = s_ohi[1][sx];
                acc += hy0 * (hx * base[oyl0 + oxl] + lx * base[oyl0 + oxh])
                     + ly0 * (hx * base[oyh0 + oxl] + lx * base[oyh0 + oxh])
                     + hy1 * (hx * base[oyl1 + oxl] + lx * base[oyl1 + oxh])
                     + ly1 * (hx * base[oyh1 + oxl] + lx * base[oyh1 + oxh]);
            }
            obase[oh * OUT + ow] = acc * 0.25f;
        }
    }
}

extern "C" void kernel_launch(void* const* d_in, const int* in_sizes, int n_in,
                              void* d_out, int out_size, void* d_ws, size_t ws_size,
                              hipStream_t stream) {
    const float* f0   = (const float*)d_in[0];
    const float* f1   = (const float*)d_in[1];
    const float* f2   = (const float*)d_in[2];
    const float* f3   = (const float*)d_in[3];
    const float* rois = (const float*)d_in[4];
    float* out = (float*)d_out;

    const size_t need_bytes = (NW0 + NW1 + NW2 + NW3) * sizeof(float);
    if (ws_size >= need_bytes) {
        float* ws0 = (float*)d_ws;
        float* ws1 = ws0 + NW0;
        float* ws2 = ws1 + NW1;
        float* ws3 = ws2 + NW2;
        transpose_f4<<<dim3((W0+31)/32, H0, 2), 256, 0, stream>>>(f0, ws0, H0, W0);
        transpose_f4<<<dim3((W1+31)/32, H1, 2), 256, 0, stream>>>(f1, ws1, H1, W1);
        transpose_f4<<<dim3((W2+31)/32, H2, 2), 256, 0, stream>>>(f2, ws2, H2, W2);
        transpose_scalar<<<dim3((W3+31)/32, H3, 2), 256, 0, stream>>>(f3, ws3, H3, W3);
        roi_gather<<<dim3(NUM_ROIS, 2), 256, 0, stream>>>(ws0, ws1, ws2, ws3, rois, out);
    } else {
        roi_extract_direct<<<NUM_ROIS, 256, 0, stream>>>(f0, f1, f2, f3, rois, out);
    }
}

// Round 4
// 102.125 us; speedup vs baseline: 9.6594x; 1.6750x over previous
//
#include <hip/hip_runtime.h>

typedef unsigned int uint32;

namespace {
constexpr int CCH = 256;   // channels
constexpr int OUT = 7;     // output size
constexpr int S   = 14;    // OUT * SAMPLE_NUM
constexpr int NUM_ROIS = 1024;

constexpr int H0 = 200, W0 = 304;
constexpr int H1 = 100, W1 = 152;
constexpr int H2 = 50,  W2 = 76;
constexpr int H3 = 25,  W3 = 38;

// transposed bf16 NHWC level sizes (in ushorts)
constexpr size_t US0 = (size_t)2 * H0 * W0 * CCH;
constexpr size_t US1 = (size_t)2 * H1 * W1 * CCH;
constexpr size_t US2 = (size_t)2 * H2 * W2 * CCH;
constexpr size_t US3 = (size_t)2 * H3 * W3 * CCH;

// fused transpose tile counts (32-x tiles per (y,b))
constexpr int T0 = 10 * H0 * 2;   // 4000
constexpr int T1 = 5  * H1 * 2;   // 1000
constexpr int T2 = 3  * H2 * 2;   // 300
constexpr int T3 = 2  * H3 * 2;   // 100
}

__device__ __forceinline__ unsigned short f2bf(float f) {
    uint32 u = __float_as_uint(f);
    u += 0x7fffu + ((u >> 16) & 1u);          // round-to-nearest-even
    return (unsigned short)(u >> 16);
}
__device__ __forceinline__ float blo(uint32 u) { return __uint_as_float(u << 16); }
__device__ __forceinline__ float bhi(uint32 u) { return __uint_as_float(u & 0xffff0000u); }

// ---------------- fused NCHW fp32 -> NHWC bf16 transpose (all levels) -------
__global__ __launch_bounds__(256) void transpose_bf16(
    const float* __restrict__ f0, const float* __restrict__ f1,
    const float* __restrict__ f2, const float* __restrict__ f3,
    unsigned short* __restrict__ o0, unsigned short* __restrict__ o1,
    unsigned short* __restrict__ o2, unsigned short* __restrict__ o3)
{
    __shared__ __align__(16) unsigned short lds[32 * 264];
    int r = blockIdx.x;
    const float* in; unsigned short* op; int H, W, TX;
    if (r < T0)           {            in = f0; op = o0; H = H0; W = W0; TX = 10; }
    else if (r < T0+T1)   { r -= T0;   in = f1; op = o1; H = H1; W = W1; TX = 5; }
    else if (r < T0+T1+T2){ r -= T0+T1; in = f2; op = o2; H = H2; W = W2; TX = 3; }
    else                  { r -= T0+T1+T2; in = f3; op = o3; H = H3; W = W3; TX = 2; }
    const int tx = r % TX; r /= TX;
    const int y = r % H;
    const int b = r / H;
    const int x0 = tx * 32;
    const int t = threadIdx.x;

    // Phase A: fp32 loads along x (float4 when aligned), convert, store [x][c]
    {
        const int xq = t & 7;          // x quad
        const int c0 = t >> 3;         // 0..31
        const int x  = x0 + 4 * xq;
        const bool w4 = ((W & 3) == 0) && (x + 3 < W);
        #pragma unroll
        for (int i = 0; i < 8; ++i) {
            const int c = c0 + (i << 5);
            const float* src = in + (((size_t)(b * CCH + c) * H + y) * W + x);
            float4 v = make_float4(0.f, 0.f, 0.f, 0.f);
            if (w4) {
                v = *reinterpret_cast<const float4*>(src);
            } else {
                if (x     < W) v.x = src[0];
                if (x + 1 < W) v.y = src[1];
                if (x + 2 < W) v.z = src[2];
                if (x + 3 < W) v.w = src[3];
            }
            unsigned short* dst = &lds[(4 * xq) * 264 + c];
            dst[0 * 264] = f2bf(v.x);
            dst[1 * 264] = f2bf(v.y);
            dst[2 * 264] = f2bf(v.z);
            dst[3 * 264] = f2bf(v.w);
        }
    }
    __syncthreads();
    // Phase B: coalesced uint4 (8 ch) stores along c
    {
        const int cg  = t & 31;        // channel group of 8
        const int xr0 = t >> 5;        // 0..7
        #pragma unroll
        for (int i = 0; i < 4; ++i) {
            const int xr = xr0 + 8 * i;
            const int x  = x0 + xr;
            if (x < W) {
                uint4 v = *reinterpret_cast<const uint4*>(&lds[xr * 264 + 8 * cg]);
                *reinterpret_cast<uint4*>(
                    op + (((size_t)b * H + y) * W + x) * CCH + 8 * cg) = v;
            }
        }
    }
}

// ---------------- gather from NHWC bf16 -------------------------------------
// One block per ROI. lane -> 4 channels (uint2 = 4 bf16); a wave covers all
// 256 channels of one bin per iteration; 4 waves split the 49 bins.
// Output staged through LDS in two halves (25 + 24 bins) to keep LDS <= 26KB.
__global__ __launch_bounds__(256) void roi_gather_bf16(
    const unsigned short* __restrict__ w0, const unsigned short* __restrict__ w1,
    const unsigned short* __restrict__ w2, const unsigned short* __restrict__ w3,
    const float* __restrict__ rois, float* __restrict__ out)
{
    const int k = blockIdx.x;
    const int t = threadIdx.x;

    __shared__ float s_wlo[2][S];
    __shared__ float s_whi[2][S];
    __shared__ int   s_olo[2][S];   // offsets in uint2 units (y: W*64, x: 64)
    __shared__ int   s_ohi[2][S];
    __shared__ __align__(16) float s_out[25 * 260];

    const float rb  = rois[k*5+0];
    const float rx1 = rois[k*5+1];
    const float ry1 = rois[k*5+2];
    const float rx2 = rois[k*5+3];
    const float ry2 = rois[k*5+4];

    const float sc = sqrtf((rx2 - rx1 + 1.0f) * (ry2 - ry1 + 1.0f));
    int lvl = (int)floorf(log2f(sc * (1.0f/56.0f) + 1e-6f));
    lvl = lvl < 0 ? 0 : (lvl > 3 ? 3 : lvl);

    const unsigned short* fp; int H, W; float sp;
    if (lvl == 0)      { fp = w0; H = H0; W = W0; sp = 0.25f;    }
    else if (lvl == 1) { fp = w1; H = H1; W = W1; sp = 0.125f;   }
    else if (lvl == 2) { fp = w2; H = H2; W = W2; sp = 0.0625f;  }
    else               { fp = w3; H = H3; W = W3; sp = 0.03125f; }

    if (t < 2*S) {
        const int axis = (t >= S) ? 1 : 0;     // 0=y, 1=x
        const int i = axis ? (t - S) : t;
        const float lo = (axis ? rx1 : ry1) * sp;
        const float hi = (axis ? rx2 : ry2) * sp;
        const int dim  = axis ? W : H;
        const float len = fmaxf(hi - lo, 1.0f);
        const float bin = len * (1.0f / (float)S);
        const float v = lo + ((float)i + 0.5f) * bin;
        const bool valid = (v >= -1.0f) && (v <= (float)dim);
        float vc = fmaxf(v, 0.0f);
        int l = (int)floorf(vc);
        if (l >= dim - 1) { vc = (float)(dim - 1); l = dim - 1; }
        const int h = min(l + 1, dim - 1);
        const float frac = vc - (float)l;
        float wlo = 1.0f - frac;
        float whi = frac;
        if (!valid) { wlo = 0.0f; whi = 0.0f; }
        const int mul = axis ? 64 : W * 64;    // uint2 units
        s_wlo[axis][i] = wlo;
        s_whi[axis][i] = whi;
        s_olo[axis][i] = l * mul;
        s_ohi[axis][i] = h * mul;
    }
    __syncthreads();

    const int b = (int)rb;
    const int lane = t & 63;
    const int wv   = t >> 6;
    const uint2* __restrict__ base =
        reinterpret_cast<const uint2*>(fp) + (size_t)b * H * W * 64 + lane;
    float* __restrict__ ob = out + (size_t)k * CCH * (OUT * OUT);

    #pragma unroll
    for (int hf = 0; hf < 2; ++hf) {
        const int bb = hf ? 25 : 0;
        const int ne = hf ? 24 : 25;

        for (int bl = wv; bl < ne; bl += 4) {
            const int bin = bb + bl;
            const int oh = bin / 7;
            const int ow = bin - oh * 7;
            const int sy0 = oh * 2, sx0 = ow * 2;
            float a0 = 0.f, a1 = 0.f, a2 = 0.f, a3 = 0.f;
            #pragma unroll
            for (int dy = 0; dy < 2; ++dy) {
                const float hy = s_wlo[0][sy0 + dy];
                const float ly = s_whi[0][sy0 + dy];
                const int oyl = s_olo[0][sy0 + dy];
                const int oyh = s_ohi[0][sy0 + dy];
                #pragma unroll
                for (int dx = 0; dx < 2; ++dx) {
                    const float hx = s_wlo[1][sx0 + dx];
                    const float lx = s_whi[1][sx0 + dx];
                    const int oxl = s_olo[1][sx0 + dx];
                    const int oxh = s_ohi[1][sx0 + dx];
                    const uint2 qll = base[oyl + oxl];
                    const uint2 qlh = base[oyl + oxh];
                    const uint2 qhl = base[oyh + oxl];
                    const uint2 qhh = base[oyh + oxh];
                    const float wll = hy * hx, wlh = hy * lx;
                    const float whl = ly * hx, whh = ly * lx;
                    a0 += wll*blo(qll.x) + wlh*blo(qlh.x) + whl*blo(qhl.x) + whh*blo(qhh.x);
                    a1 += wll*bhi(qll.x) + wlh*bhi(qlh.x) + whl*bhi(qhl.x) + whh*bhi(qhh.x);
                    a2 += wll*blo(qll.y) + wlh*blo(qlh.y) + whl*blo(qhl.y) + whh*blo(qhh.y);
                    a3 += wll*bhi(qll.y) + wlh*bhi(qlh.y) + whl*bhi(qhl.y) + whh*bhi(qhh.y);
                }
            }
            float4 res = make_float4(a0*0.25f, a1*0.25f, a2*0.25f, a3*0.25f);
            *reinterpret_cast<float4*>(&s_out[bl * 260 + 4 * lane]) = res;
        }
        __syncthreads();

        // dump: 256*ne elements, c-major flat index for near-coalesced stores
        #pragma unroll 1
        for (int j = 0; j < ne; ++j) {
            const int f = t + j * 256;
            const int c = f / ne;          // ne is compile-time after unroll(hf)
            const int bl = f - c * ne;
            ob[c * (OUT*OUT) + bb + bl] = s_out[bl * 260 + c];
        }
        __syncthreads();
    }
}

// ---------------- fallback (direct NCHW fp32) if ws too small ---------------
__global__ __launch_bounds__(256) void roi_extract_direct(
    const float* __restrict__ f0, const float* __restrict__ f1,
    const float* __restrict__ f2, const float* __restrict__ f3,
    const float* __restrict__ rois, float* __restrict__ out)
{
    const int k = blockIdx.x;
    const int t = threadIdx.x;

    __shared__ float s_wlo[2][S];
    __shared__ float s_whi[2][S];
    __shared__ int   s_olo[2][S];
    __shared__ int   s_ohi[2][S];

    const float rb  = rois[k*5+0];
    const float rx1 = rois[k*5+1];
    const float ry1 = rois[k*5+2];
    const float rx2 = rois[k*5+3];
    const float ry2 = rois[k*5+4];

    const float sc = sqrtf((rx2 - rx1 + 1.0f) * (ry2 - ry1 + 1.0f));
    int lvl = (int)floorf(log2f(sc * (1.0f/56.0f) + 1e-6f));
    lvl = lvl < 0 ? 0 : (lvl > 3 ? 3 : lvl);

    const float* fp; int H, W; float sp;
    if (lvl == 0)      { fp = f0; H = H0; W = W0; sp = 0.25f;    }
    else if (lvl == 1) { fp = f1; H = H1; W = W1; sp = 0.125f;   }
    else if (lvl == 2) { fp = f2; H = H2; W = W2; sp = 0.0625f;  }
    else               { fp = f3; H = H3; W = W3; sp = 0.03125f; }

    if (t < 2*S) {
        const int axis = (t >= S) ? 1 : 0;
        const int i = axis ? (t - S) : t;
        const float lo = (axis ? rx1 : ry1) * sp;
        const float hi = (axis ? rx2 : ry2) * sp;
        const int dim  = axis ? W : H;
        const float len = fmaxf(hi - lo, 1.0f);
        const float bin = len * (1.0f / (float)S);
        const float v = lo + ((float)i + 0.5f) * bin;
        const bool valid = (v >= -1.0f) && (v <= (float)dim);
        float vc = fmaxf(v, 0.0f);
        int l = (int)floorf(vc);
        if (l >= dim - 1) { vc = (float)(dim - 1); l = dim - 1; }
        const int h = min(l + 1, dim - 1);
        const float frac = vc - (float)l;
        float wlo = 1.0f - frac;
        float whi = frac;
        if (!valid) { wlo = 0.0f; whi = 0.0f; }
        const int mul = axis ? 1 : W;
        s_wlo[axis][i] = wlo;
        s_whi[axis][i] = whi;
        s_olo[axis][i] = l * mul;
        s_ohi[axis][i] = h * mul;
    }
    __syncthreads();

    const int b = (int)rb;
    const float* __restrict__ base = fp + (size_t)(b * CCH + t) * (size_t)(H * W);
    float* __restrict__ obase = out + ((size_t)k * CCH + t) * (OUT * OUT);

    for (int oh = 0; oh < OUT; ++oh) {
        const int sy0 = oh * 2;
        const float hy0 = s_wlo[0][sy0],   ly0 = s_whi[0][sy0];
        const float hy1 = s_wlo[0][sy0+1], ly1 = s_whi[0][sy0+1];
        const int oyl0 = s_olo[0][sy0],   oyh0 = s_ohi[0][sy0];
        const int oyl1 = s_olo[0][sy0+1], oyh1 = s_ohi[0][sy0+1];
        #pragma unroll
        for (int ow = 0; ow < OUT; ++ow) {
            float acc = 0.0f;
            #pragma unroll
            for (int dx = 0; dx < 2; ++dx) {
                const int sx = ow * 2 + dx;
                const float hx = s_wlo[1][sx];
                const float lx = s_whi[1][sx];
                const int oxl = s_olo[1][sx];
                const int oxh = s_ohi[1][sx];
                acc += hy0 * (hx * base[oyl0 + oxl] + lx * base[oyl0 + oxh])
                     + ly0 * (hx * base[oyh0 + oxl] + lx * base[oyh0 + oxh])
                     + hy1 * (hx * base[oyl1 + oxl] + lx * base[oyl1 + oxh])
                     + ly1 * (hx * base[oyh1 + oxl] + lx * base[oyh1 + oxh]);
            }
            obase[oh * OUT + ow] = acc * 0.25f;
        }
    }
}

extern "C" void kernel_launch(void* const* d_in, const int* in_sizes, int n_in,
                              void* d_out, int out_size, void* d_ws, size_t ws_size,
                              hipStream_t stream) {
    const float* f0   = (const float*)d_in[0];
    const float* f1   = (const float*)d_in[1];
    const float* f2   = (const float*)d_in[2];
    const float* f3   = (const float*)d_in[3];
    const float* rois = (const float*)d_in[4];
    float* out = (float*)d_out;

    const size_t need_bytes = (US0 + US1 + US2 + US3) * sizeof(unsigned short);
    if (ws_size >= need_bytes) {
        unsigned short* ws0 = (unsigned short*)d_ws;
        unsigned short* ws1 = ws0 + US0;
        unsigned short* ws2 = ws1 + US1;
        unsigned short* ws3 = ws2 + US2;
        transpose_bf16<<<T0 + T1 + T2 + T3, 256, 0, stream>>>(
            f0, f1, f2, f3, ws0, ws1, ws2, ws3);
        roi_gather_bf16<<<NUM_ROIS, 256, 0, stream>>>(ws0, ws1, ws2, ws3, rois, out);
    } else {
        roi_extract_direct<<<NUM_ROIS, 256, 0, stream>>>(f0, f1, f2, f3, rois, out);
    }
}